// Round 1
// baseline (586.758 us; speedup 1.0000x reference)
//
#include <hip/hip_runtime.h>
#include <hip/hip_bf16.h>

// Problem constants (match reference setup_inputs()).
#define NN 30000
#define EE 480000
#define RR 8
#define BB 4
#define HH 128
// OUT == HH == 128

typedef __attribute__((ext_vector_type(8))) short short8;
typedef __attribute__((ext_vector_type(4))) float float4v;

__device__ __forceinline__ float bf2f(unsigned short u) {
    union { unsigned int i; float f; } c; c.i = ((unsigned int)u) << 16; return c.f;
}
__device__ __forceinline__ unsigned short f2bf(float f) {
    union { float f; unsigned int i; } c; c.f = f;
    unsigned int r = c.i + 0x7fffu + ((c.i >> 16) & 1u);
    return (unsigned short)(r >> 16);
}

// ---------------- CSR build ----------------
__global__ void k_hist(const int* __restrict__ dst, int* __restrict__ cnt) {
    int i = blockIdx.x * 256 + threadIdx.x;
    if (i < EE) atomicAdd(&cnt[dst[i]], 1);
}

// Single block, 1024 threads: exclusive scan of cnt[0..n) -> row_ptr[0..n],
// and rewrite cnt (same buffer) with the exclusive value (becomes the cursor).
__global__ void k_scan(int* __restrict__ cnt_cursor, int* __restrict__ row_ptr) {
    __shared__ int buf[1024];
    __shared__ int carry_s;
    int tid = threadIdx.x;
    if (tid == 0) carry_s = 0;
    __syncthreads();
    for (int base = 0; base < NN; base += 1024) {
        int i = base + tid;
        int v = (i < NN) ? cnt_cursor[i] : 0;
        buf[tid] = v;
        __syncthreads();
        for (int off = 1; off < 1024; off <<= 1) {
            int t = (tid >= off) ? buf[tid - off] : 0;
            __syncthreads();
            if (tid >= off) buf[tid] += t;
            __syncthreads();
        }
        int excl = buf[tid] - v;
        int carry = carry_s;
        if (i < NN) {
            row_ptr[i] = carry + excl;
            cnt_cursor[i] = carry + excl;
        }
        __syncthreads();
        if (tid == 1023) carry_s = carry + buf[1023];
        __syncthreads();
    }
    if (tid == 0) row_ptr[NN] = carry_s;
}

__global__ void k_scatter(const int* __restrict__ dst, int* __restrict__ cursor,
                          int* __restrict__ eid) {
    int i = blockIdx.x * 256 + threadIdx.x;
    if (i < EE) {
        int pos = atomicAdd(&cursor[dst[i]], 1);
        eid[pos] = i;
    }
}

// ---------------- Weight prep ----------------
// Wfull[r][n][h] = sum_b comp_in[r][b] * V_in[b][n][h]   (bf16 out)
__global__ void k_wfull(const float* __restrict__ V_in, const float* __restrict__ comp_in,
                        unsigned short* __restrict__ table) {
    int idx = blockIdx.x * 256 + threadIdx.x;   // over N*H = 3,840,000
    if (idx >= NN * HH) return;
    float v0 = V_in[0 * NN * HH + idx];
    float v1 = V_in[1 * NN * HH + idx];
    float v2 = V_in[2 * NN * HH + idx];
    float v3 = V_in[3 * NN * HH + idx];
#pragma unroll
    for (int r = 0; r < RR; ++r) {
        float o = comp_in[r * BB + 0] * v0 + comp_in[r * BB + 1] * v1 +
                  comp_in[r * BB + 2] * v2 + comp_in[r * BB + 3] * v3;
        table[r * NN * HH + idx] = f2bf(o);
    }
}

// Wt[row = r*128 + j][k] = sum_b comp[r][b] * V[b][k][j]  (B^T layout for MFMA B-frags)
__global__ void k_weights(const float* __restrict__ V_h, const float* __restrict__ comp_h,
                          const float* __restrict__ V_o, const float* __restrict__ comp_o,
                          unsigned short* __restrict__ Wt_h, unsigned short* __restrict__ Wt_o) {
    int idx = blockIdx.x * 256 + threadIdx.x;   // over 2 * 8*128*128 = 262144
    if (idx >= 2 * RR * HH * HH) return;
    int which = idx >> 17;
    int local = idx & 0x1FFFF;
    const float* V = which ? V_o : V_h;
    const float* comp = which ? comp_o : comp_h;
    unsigned short* W = which ? Wt_o : Wt_h;
    int k = local & 127;
    int row = local >> 7;
    int j = row & 127;
    int r = row >> 7;
    float acc = 0.f;
#pragma unroll
    for (int b = 0; b < BB; ++b)
        acc += comp[r * BB + b] * V[(b * HH + k) * HH + j];
    W[local] = f2bf(acc);
}

// ---------------- Edge aggregation (CSR, block = 1 dst node, 128 threads) -------------
__global__ __launch_bounds__(128)
void k_agg(const unsigned short* __restrict__ table, const int* __restrict__ row_ptr,
           const int* __restrict__ eid, const int* __restrict__ src,
           const int* __restrict__ rel, const float* __restrict__ norm,
           const float* __restrict__ bias, unsigned short* __restrict__ out_bf,
           float* __restrict__ out_f, int do_relu) {
    __shared__ int s_row[128];
    __shared__ float s_w[128];
    int d = blockIdx.x;
    int h = threadIdx.x;
    int rs = row_ptr[d], re = row_ptr[d + 1];
    float acc = 0.f;
    for (int base = rs; base < re; base += 128) {
        int cnt = min(128, re - base);
        if (h < cnt) {
            int e = eid[base + h];
            s_row[h] = (rel[e] * NN + src[e]) * HH;
            s_w[h] = norm[e];
        }
        __syncthreads();
        for (int j = 0; j < cnt; ++j)
            acc += s_w[j] * bf2f(table[s_row[j] + h]);
        __syncthreads();
    }
    acc += bias[h];
    if (do_relu) acc = fmaxf(acc, 0.f);
    if (out_bf) out_bf[d * HH + h] = f2bf(acc);
    if (out_f) out_f[d * HH + h] = acc;
}

// ---------------- GEMM: T[r][n][h] = (A @ W_r)[n][h], A bf16 [30000][128] -------------
// Bt (=Wt) is [1024][128] with Bt[j][k] = W_{j>>7}[k][j&127].
// One wave computes a 16(M) x 64(N) strip; K = 128 = 4 MFMA steps.
__global__ __launch_bounds__(256)
void k_gemm(const unsigned short* __restrict__ A, const unsigned short* __restrict__ Bt,
            unsigned short* __restrict__ T) {
    int tid = threadIdx.x;
    int wid = blockIdx.x * 4 + (tid >> 6);      // 30000 waves total
    int lane = tid & 63;
    int mtile = wid >> 4;                        // 0..1874
    int nstrip = wid & 15;                       // 0..15
    int m0 = mtile * 16;
    int n0 = nstrip * 64;
    int mr = lane & 15;
    int kq = lane >> 4;

    float4v acc0 = {0.f, 0.f, 0.f, 0.f};
    float4v acc1 = {0.f, 0.f, 0.f, 0.f};
    float4v acc2 = {0.f, 0.f, 0.f, 0.f};
    float4v acc3 = {0.f, 0.f, 0.f, 0.f};

    const unsigned short* arow = A + (m0 + mr) * HH + kq * 8;
#pragma unroll
    for (int kk = 0; kk < 4; ++kk) {
        short8 a = *(const short8*)(arow + kk * 32);
        short8 b0 = *(const short8*)(Bt + (n0 + 0 * 16 + mr) * HH + kk * 32 + kq * 8);
        short8 b1 = *(const short8*)(Bt + (n0 + 1 * 16 + mr) * HH + kk * 32 + kq * 8);
        short8 b2 = *(const short8*)(Bt + (n0 + 2 * 16 + mr) * HH + kk * 32 + kq * 8);
        short8 b3 = *(const short8*)(Bt + (n0 + 3 * 16 + mr) * HH + kk * 32 + kq * 8);
        acc0 = __builtin_amdgcn_mfma_f32_16x16x32_bf16(a, b0, acc0, 0, 0, 0);
        acc1 = __builtin_amdgcn_mfma_f32_16x16x32_bf16(a, b1, acc1, 0, 0, 0);
        acc2 = __builtin_amdgcn_mfma_f32_16x16x32_bf16(a, b2, acc2, 0, 0, 0);
        acc3 = __builtin_amdgcn_mfma_f32_16x16x32_bf16(a, b3, acc3, 0, 0, 0);
    }

    // C/D layout: col = lane&15, row = (lane>>4)*4 + i  [measured m89]
#pragma unroll
    for (int t = 0; t < 4; ++t) {
        float4v acc = t == 0 ? acc0 : (t == 1 ? acc1 : (t == 2 ? acc2 : acc3));
#pragma unroll
        for (int i = 0; i < 4; ++i) {
            int node = m0 + kq * 4 + i;
            int col = n0 + t * 16 + mr;
            int r = col >> 7;
            int hc = col & 127;
            T[(r * NN + node) * HH + hc] = f2bf(acc[i]);
        }
    }
}

// ---------------- Pooling ----------------
__global__ void k_logits(const float* __restrict__ h3, const float* __restrict__ gW,
                         const float* __restrict__ gb, float* __restrict__ logits) {
    int wid = (blockIdx.x * 256 + threadIdx.x) >> 6;
    int lane = threadIdx.x & 63;
    if (wid >= NN) return;
    const float* row = h3 + wid * HH;
    float v = row[lane] * gW[lane] + row[lane + 64] * gW[lane + 64];
#pragma unroll
    for (int off = 32; off; off >>= 1) v += __shfl_down(v, off);
    if (lane == 0) logits[wid] = v + gb[0];
}

__global__ void k_smax(const float* __restrict__ logits, float* __restrict__ scal) {
    __shared__ float buf[1024];
    int tid = threadIdx.x;
    float m = -1e30f;
    for (int i = tid; i < NN; i += 1024) m = fmaxf(m, logits[i]);
    buf[tid] = m;
    __syncthreads();
    for (int off = 512; off; off >>= 1) {
        if (tid < off) buf[tid] = fmaxf(buf[tid], buf[tid + off]);
        __syncthreads();
    }
    float mx = buf[0];
    __syncthreads();
    float s = 0.f;
    for (int i = tid; i < NN; i += 1024) s += expf(logits[i] - mx);
    buf[tid] = s;
    __syncthreads();
    for (int off = 512; off; off >>= 1) {
        if (tid < off) buf[tid] += buf[tid + off];
        __syncthreads();
    }
    if (tid == 0) { scal[0] = mx; scal[1] = buf[0]; }
}

__global__ void k_weightify(float* __restrict__ logits, const float* __restrict__ scal) {
    int i = blockIdx.x * 256 + threadIdx.x;
    if (i < NN) logits[i] = expf(logits[i] - scal[0]) / scal[1];
}

__global__ __launch_bounds__(128)
void k_out(const float* __restrict__ h3, const float* __restrict__ w,
           float* __restrict__ out) {
    int h = threadIdx.x;
    int n0 = blockIdx.x * 256;
    int n1 = min(n0 + 256, NN);
    float acc = 0.f;
    for (int n = n0; n < n1; ++n) acc += w[n] * h3[n * HH + h];
    atomicAdd(&out[h], acc);
}

extern "C" void kernel_launch(void* const* d_in, const int* in_sizes, int n_in,
                              void* d_out, int out_size, void* d_ws, size_t ws_size,
                              hipStream_t stream) {
    const int* src = (const int*)d_in[1];
    const int* dst = (const int*)d_in[2];
    const int* rel = (const int*)d_in[3];
    const float* norm = (const float*)d_in[4];
    const float* V_in = (const float*)d_in[5];
    const float* comp_in = (const float*)d_in[6];
    const float* bias_in = (const float*)d_in[7];
    const float* V_h = (const float*)d_in[8];
    const float* comp_h = (const float*)d_in[9];
    const float* bias_h = (const float*)d_in[10];
    const float* V_out = (const float*)d_in[11];
    const float* comp_out = (const float*)d_in[12];
    const float* bias_out = (const float*)d_in[13];
    const float* gate_W = (const float*)d_in[14];
    const float* gate_b = (const float*)d_in[15];
    float* out = (float*)d_out;

    // Workspace layout (~95 MB total)
    char* ws = (char*)d_ws;
    unsigned short* table = (unsigned short*)ws;                   // 61,440,000 B  (R*N*H bf16)
    unsigned short* h1b = (unsigned short*)(ws + 61440000);        //  7,680,000
    unsigned short* h2b = (unsigned short*)(ws + 69120000);        //  7,680,000
    float* h3f = (float*)(ws + 76800000);                          // 15,360,000
    unsigned short* Wt_h = (unsigned short*)(ws + 92160000);       //    262,144
    unsigned short* Wt_o = (unsigned short*)(ws + 92422144);       //    262,144
    int* row_ptr = (int*)(ws + 92684288);                          //    120,064 (padded)
    int* cursor = (int*)(ws + 92804352);                           //    120,064
    int* eid = (int*)(ws + 92924416);                              //  1,920,000
    float* logits = (float*)(ws + 94844416);                       //    120,000
    float* scal = (float*)(ws + 94964416);                         //          8

    // ---- CSR by dst ----
    hipMemsetAsync(cursor, 0, NN * sizeof(int), stream);
    k_hist<<<(EE + 255) / 256, 256, 0, stream>>>(dst, cursor);
    k_scan<<<1, 1024, 0, stream>>>(cursor, row_ptr);
    k_scatter<<<(EE + 255) / 256, 256, 0, stream>>>(dst, cursor, eid);

    // ---- weights ----
    k_wfull<<<(NN * HH + 255) / 256, 256, 0, stream>>>(V_in, comp_in, table);
    k_weights<<<(2 * RR * HH * HH + 255) / 256, 256, 0, stream>>>(V_h, comp_h, V_out, comp_out,
                                                                  Wt_h, Wt_o);

    // ---- layer 1 ----
    k_agg<<<NN, 128, 0, stream>>>(table, row_ptr, eid, src, rel, norm, bias_in,
                                  h1b, (float*)nullptr, 1);
    // ---- layer 2 ----
    k_gemm<<<NN / 4, 256, 0, stream>>>(h1b, Wt_h, table);
    k_agg<<<NN, 128, 0, stream>>>(table, row_ptr, eid, src, rel, norm, bias_h,
                                  h2b, (float*)nullptr, 1);
    // ---- layer 3 ----
    k_gemm<<<NN / 4, 256, 0, stream>>>(h2b, Wt_o, table);
    k_agg<<<NN, 128, 0, stream>>>(table, row_ptr, eid, src, rel, norm, bias_out,
                                  (unsigned short*)nullptr, h3f, 0);

    // ---- attention pooling ----
    k_logits<<<(NN + 3) / 4, 256, 0, stream>>>(h3f, gate_W, gate_b, logits);
    k_smax<<<1, 1024, 0, stream>>>(logits, scal);
    k_weightify<<<(NN + 255) / 256, 256, 0, stream>>>(logits, scal);
    hipMemsetAsync(out, 0, 128 * sizeof(float), stream);
    k_out<<<(NN + 255) / 256, 128, 0, stream>>>(h3f, logits, out);
}

// Round 2
// 466.577 us; speedup vs baseline: 1.2576x; 1.2576x over previous
//
#include <hip/hip_runtime.h>
#include <hip/hip_bf16.h>

// Problem constants (match reference setup_inputs()).
#define NN 30000
#define EE 480000
#define RR 8
#define BB 4
#define HH 128
#define NH (NN * HH)          // 3,840,000

typedef __attribute__((ext_vector_type(8))) short short8;
typedef __attribute__((ext_vector_type(4))) short short4v;
typedef __attribute__((ext_vector_type(4))) float float4v;

__device__ __forceinline__ unsigned short f2bf(float f) {
    union { float f; unsigned int i; } c; c.f = f;
    unsigned int r = c.i + 0x7fffu + ((c.i >> 16) & 1u);
    return (unsigned short)(r >> 16);
}
__device__ __forceinline__ float bflo(unsigned int v) {
    union { unsigned int i; float f; } c; c.i = v << 16; return c.f;
}
__device__ __forceinline__ float bfhi(unsigned int v) {
    union { unsigned int i; float f; } c; c.i = v & 0xFFFF0000u; return c.f;
}
__device__ __forceinline__ unsigned int packbf(float a, float b) {
    return (unsigned int)f2bf(a) | ((unsigned int)f2bf(b) << 16);
}

// ---------------- CSR build ----------------
__global__ void k_hist(const int* __restrict__ dst, int* __restrict__ cnt) {
    int i = blockIdx.x * 256 + threadIdx.x;
    if (i < EE) atomicAdd(&cnt[dst[i]], 1);
}

// Single block, 1024 threads, shuffle-based scan (3 barriers per 1024-chunk).
__global__ void k_scan(int* __restrict__ cc, int* __restrict__ rp) {
    __shared__ int ws[16];
    __shared__ int chunk_carry;
    int tid = threadIdx.x, lane = tid & 63, wid = tid >> 6;
    if (tid == 0) chunk_carry = 0;
    __syncthreads();
    for (int base = 0; base < NN; base += 1024) {
        int i = base + tid;
        int v = (i < NN) ? cc[i] : 0;
        int incl = v;
#pragma unroll
        for (int d = 1; d < 64; d <<= 1) {
            int t = __shfl_up(incl, d);
            if (lane >= d) incl += t;
        }
        if (lane == 63) ws[wid] = incl;
        __syncthreads();
        if (wid == 0) {
            int s = (lane < 16) ? ws[lane] : 0;
#pragma unroll
            for (int d = 1; d < 16; d <<= 1) {
                int t = __shfl_up(s, d);
                if (lane >= d) s += t;
            }
            if (lane < 16) ws[lane] = s;   // inclusive wave sums
        }
        __syncthreads();
        int wave_off = (wid == 0) ? 0 : ws[wid - 1];
        int excl = chunk_carry + wave_off + (incl - v);
        if (i < NN) { rp[i] = excl; cc[i] = excl; }
        __syncthreads();
        if (tid == 0) chunk_carry += ws[15];
        __syncthreads();
    }
    if (threadIdx.x == 0) rp[NN] = chunk_carry;
}

// Scatter packed edge meta into CSR order: x = src*64 | (rel<<24), y = bits(norm)
__global__ void k_scatter(const int* __restrict__ dst, const int* __restrict__ src,
                          const int* __restrict__ rel, const float* __restrict__ norm,
                          int* __restrict__ cursor, uint2* __restrict__ meta) {
    int i = blockIdx.x * 256 + threadIdx.x;
    if (i < EE) {
        int pos = atomicAdd(&cursor[dst[i]], 1);
        meta[pos] = make_uint2((unsigned int)(src[i] * 64) | ((unsigned int)rel[i] << 24),
                               __float_as_uint(norm[i]));
    }
}

// ---------------- Weight prep ----------------
// table[r][n][h] = sum_b comp_in[r][b] * V_in[b][n][h]   (bf16)
__global__ void k_wfull(const float* __restrict__ V_in, const float* __restrict__ comp_in,
                        unsigned short* __restrict__ table) {
    int idx = (blockIdx.x * 256 + threadIdx.x) * 4;
    if (idx >= NH) return;
    float4v v0 = *(const float4v*)(V_in + idx);
    float4v v1 = *(const float4v*)(V_in + NH + idx);
    float4v v2 = *(const float4v*)(V_in + 2 * NH + idx);
    float4v v3 = *(const float4v*)(V_in + 3 * NH + idx);
#pragma unroll
    for (int r = 0; r < RR; ++r) {
        float c0 = comp_in[r * 4 + 0], c1 = comp_in[r * 4 + 1];
        float c2 = comp_in[r * 4 + 2], c3 = comp_in[r * 4 + 3];
        float4v o = c0 * v0 + c1 * v1 + c2 * v2 + c3 * v3;
        short4v s;
#pragma unroll
        for (int t = 0; t < 4; ++t) s[t] = (short)f2bf(o[t]);
        *(short4v*)(table + r * NH + idx) = s;
    }
}

// Bt[j][kk] = Vflat[kk][j],  Vflat = V reshaped [512][128]  (B^T for MFMA B-frags)
__global__ void k_weights(const float* __restrict__ V_h, const float* __restrict__ V_o,
                          unsigned short* __restrict__ Bt_h, unsigned short* __restrict__ Bt_o) {
    int idx = blockIdx.x * 256 + threadIdx.x;   // 2 * 128 * 512 = 131072
    if (idx >= 2 * 128 * 512) return;
    int which = idx >> 16;
    int local = idx & 0xFFFF;
    int j = local >> 9;
    int kk = local & 511;
    const float* V = which ? V_o : V_h;
    unsigned short* W = which ? Bt_o : Bt_h;
    W[j * 512 + kk] = f2bf(V[kk * 128 + j]);
}

// ---------------- Layer-1 aggregation: gather table rows, weight by norm --------------
// One wave per dst node, lane covers channels (2l, 2l+1).
__global__ __launch_bounds__(256)
void k_agg1(const unsigned int* __restrict__ table_u, const int* __restrict__ row_ptr,
            const uint2* __restrict__ meta, const float* __restrict__ bias,
            unsigned int* __restrict__ h1u) {
    int lane = threadIdx.x & 63;
    int d = blockIdx.x * 4 + (threadIdx.x >> 6);
    int rs = row_ptr[d], re = row_ptr[d + 1];
    float a0 = 0.f, a1 = 0.f;
    for (int base = rs; base < re; base += 64) {
        int cnt = re - base; if (cnt > 64) cnt = 64;
        int rowm = 0; float wm = 0.f;
        if (lane < cnt) {
            uint2 m = meta[base + lane];
            rowm = (int)((m.x >> 24) * (unsigned int)(NN * 64) + (m.x & 0xFFFFFFu));
            wm = __uint_as_float(m.y);
        }
        for (int j = 0; j < cnt; ++j) {
            int row = __shfl(rowm, j);
            float w = __shfl(wm, j);
            unsigned int v = table_u[row + lane];
            a0 += w * bflo(v);
            a1 += w * bfhi(v);
        }
    }
    a0 += bias[2 * lane];     a1 += bias[2 * lane + 1];
    a0 = fmaxf(a0, 0.f);      a1 = fmaxf(a1, 0.f);
    h1u[d * 64 + lane] = packbf(a0, a1);
}

// ---------------- Basis-weighted aggregation: g[d][b*128+h] = sum_e c[rel,b] norm h[src][h]
__global__ __launch_bounds__(256)
void k_aggb(const unsigned int* __restrict__ hu, const int* __restrict__ row_ptr,
            const uint2* __restrict__ meta, const float* __restrict__ comp,
            unsigned int* __restrict__ gu) {
    int lane = threadIdx.x & 63;
    int d = blockIdx.x * 4 + (threadIdx.x >> 6);
    int rs = row_ptr[d], re = row_ptr[d + 1];
    float a00 = 0, a01 = 0, a10 = 0, a11 = 0, a20 = 0, a21 = 0, a30 = 0, a31 = 0;
    for (int base = rs; base < re; base += 64) {
        int cnt = re - base; if (cnt > 64) cnt = 64;
        int offm = 0; float w0m = 0, w1m = 0, w2m = 0, w3m = 0;
        if (lane < cnt) {
            uint2 m = meta[base + lane];
            offm = (int)(m.x & 0xFFFFFFu);
            int r4 = (int)(m.x >> 24) * 4;
            float nm = __uint_as_float(m.y);
            w0m = comp[r4 + 0] * nm; w1m = comp[r4 + 1] * nm;
            w2m = comp[r4 + 2] * nm; w3m = comp[r4 + 3] * nm;
        }
        for (int j = 0; j < cnt; ++j) {
            int off = __shfl(offm, j);
            float w0 = __shfl(w0m, j), w1 = __shfl(w1m, j);
            float w2 = __shfl(w2m, j), w3 = __shfl(w3m, j);
            unsigned int v = hu[off + lane];
            float f0 = bflo(v), f1 = bfhi(v);
            a00 += w0 * f0; a01 += w0 * f1;
            a10 += w1 * f0; a11 += w1 * f1;
            a20 += w2 * f0; a21 += w2 * f1;
            a30 += w3 * f0; a31 += w3 * f1;
        }
    }
    gu[d * 256 +       lane] = packbf(a00, a01);
    gu[d * 256 +  64 + lane] = packbf(a10, a11);
    gu[d * 256 + 128 + lane] = packbf(a20, a21);
    gu[d * 256 + 192 + lane] = packbf(a30, a31);
}

// ---------------- GEMM: out[n][j] = relu?(g[n] @ Bt^T + bias), M=30016 N=128 K=512 -----
// Wave computes 16 rows x 128 cols; K-loop 16 MFMA steps x 8 col-frags.
__global__ __launch_bounds__(256)
void k_gemm2(const unsigned short* __restrict__ A, const unsigned short* __restrict__ Bt,
             const float* __restrict__ bias, unsigned int* __restrict__ outu, int relu) {
    __shared__ float lds[64 * 132];
    int tid = threadIdx.x;
    int w = tid >> 6, lane = tid & 63;
    int mr = lane & 15, kq = lane >> 4;
    int m0 = (blockIdx.x * 4 + w) * 16;
    float4v z = {0.f, 0.f, 0.f, 0.f};
    float4v acc[8];
#pragma unroll
    for (int c = 0; c < 8; ++c) acc[c] = z;
    const unsigned short* arow = A + (m0 + mr) * 512 + kq * 8;
    const unsigned short* brow = Bt + mr * 512 + kq * 8;
#pragma unroll
    for (int kk = 0; kk < 16; ++kk) {
        short8 a = *(const short8*)(arow + kk * 32);
#pragma unroll
        for (int c = 0; c < 8; ++c) {
            short8 b = *(const short8*)(brow + c * 16 * 512 + kk * 32);
            acc[c] = __builtin_amdgcn_mfma_f32_16x16x32_bf16(a, b, acc[c], 0, 0, 0);
        }
    }
    // C/D layout: col = lane&15, row = (lane>>4)*4 + i  -> stage to LDS, store coalesced
#pragma unroll
    for (int c = 0; c < 8; ++c)
#pragma unroll
        for (int i = 0; i < 4; ++i)
            lds[(w * 16 + kq * 4 + i) * 132 + c * 16 + mr] = acc[c][i];
    __syncthreads();
    float b0 = bias[2 * lane], b1 = bias[2 * lane + 1];
    for (int it = 0; it < 16; ++it) {
        int node = m0 + it;
        if (node < NN) {
            float f0 = lds[(w * 16 + it) * 132 + 2 * lane] + b0;
            float f1 = lds[(w * 16 + it) * 132 + 2 * lane + 1] + b1;
            if (relu) { f0 = fmaxf(f0, 0.f); f1 = fmaxf(f1, 0.f); }
            outu[node * 64 + lane] = packbf(f0, f1);
        }
    }
}

// ---------------- Pooling ----------------
__global__ __launch_bounds__(256)
void k_logits(const unsigned int* __restrict__ h3u, const float* __restrict__ gW,
              const float* __restrict__ gb, float* __restrict__ logits) {
    int lane = threadIdx.x & 63;
    int n = blockIdx.x * 4 + (threadIdx.x >> 6);
    unsigned int v = h3u[n * 64 + lane];
    float s = bflo(v) * gW[2 * lane] + bfhi(v) * gW[2 * lane + 1];
#pragma unroll
    for (int off = 32; off; off >>= 1) s += __shfl_down(s, off);
    if (lane == 0) logits[n] = s + gb[0];
}

__global__ void k_smax(const float* __restrict__ logits, float* __restrict__ scal) {
    __shared__ float buf[1024];
    int tid = threadIdx.x;
    float m = -1e30f;
    for (int i = tid; i < NN; i += 1024) m = fmaxf(m, logits[i]);
    buf[tid] = m;
    __syncthreads();
    for (int off = 512; off; off >>= 1) {
        if (tid < off) buf[tid] = fmaxf(buf[tid], buf[tid + off]);
        __syncthreads();
    }
    float mx = buf[0];
    __syncthreads();
    float s = 0.f;
    for (int i = tid; i < NN; i += 1024) s += expf(logits[i] - mx);
    buf[tid] = s;
    __syncthreads();
    for (int off = 512; off; off >>= 1) {
        if (tid < off) buf[tid] += buf[tid + off];
        __syncthreads();
    }
    if (tid == 0) { scal[0] = mx; scal[1] = buf[0]; }
}

// out[2h,2h+1] += sum_n softmax_w(n) * h3[n][2h,2h+1]   (weightify fused)
__global__ __launch_bounds__(64)
void k_out(const unsigned int* __restrict__ h3u, const float* __restrict__ logits,
           const float* __restrict__ scal, float* __restrict__ out) {
    int h = threadIdx.x;
    int n0 = blockIdx.x * 64;
    int n1 = n0 + 64; if (n1 > NN) n1 = NN;
    float s0 = scal[0], inv = 1.f / scal[1];
    float a0 = 0.f, a1 = 0.f;
    for (int n = n0; n < n1; ++n) {
        float wgt = __expf(logits[n] - s0) * inv;
        unsigned int v = h3u[n * 64 + h];
        a0 += wgt * bflo(v);
        a1 += wgt * bfhi(v);
    }
    atomicAdd(&out[2 * h], a0);
    atomicAdd(&out[2 * h + 1], a1);
}

extern "C" void kernel_launch(void* const* d_in, const int* in_sizes, int n_in,
                              void* d_out, int out_size, void* d_ws, size_t ws_size,
                              hipStream_t stream) {
    const int* src = (const int*)d_in[1];
    const int* dst = (const int*)d_in[2];
    const int* rel = (const int*)d_in[3];
    const float* norm = (const float*)d_in[4];
    const float* V_in = (const float*)d_in[5];
    const float* comp_in = (const float*)d_in[6];
    const float* bias_in = (const float*)d_in[7];
    const float* V_h = (const float*)d_in[8];
    const float* comp_h = (const float*)d_in[9];
    const float* bias_h = (const float*)d_in[10];
    const float* V_out = (const float*)d_in[11];
    const float* comp_out = (const float*)d_in[12];
    const float* bias_out = (const float*)d_in[13];
    const float* gate_W = (const float*)d_in[14];
    const float* gate_b = (const float*)d_in[15];
    float* out = (float*)d_out;

    // Workspace layout (~88.9 MB). g reuses the table region (table dead after agg1).
    char* ws = (char*)d_ws;
    unsigned short* table = (unsigned short*)ws;                 // 61,440,000 B (R*N*H bf16)
    unsigned short* g = (unsigned short*)ws;                     // 30,736,384 B (30016*512 bf16)
    unsigned int* h1u = (unsigned int*)(ws + 61440000);          //  7,680,000
    unsigned int* h2u = (unsigned int*)(ws + 69120000);          //  7,680,000
    unsigned int* h3u = (unsigned int*)(ws + 76800000);          //  7,680,000
    unsigned short* Bt_h = (unsigned short*)(ws + 84480000);     //    131,072
    unsigned short* Bt_o = (unsigned short*)(ws + 84611072);     //    131,072
    int* row_ptr = (int*)(ws + 84742144);                        //    120,064
    int* cursor = (int*)(ws + 84862208);                         //    120,064
    uint2* meta = (uint2*)(ws + 84982272);                       //  3,840,000
    float* logits = (float*)(ws + 88822272);                     //    120,000
    float* scal = (float*)(ws + 88942272);                       //          8

    // ---- CSR by dst (packed meta) ----
    hipMemsetAsync(cursor, 0, NN * sizeof(int), stream);
    k_hist<<<(EE + 255) / 256, 256, 0, stream>>>(dst, cursor);
    k_scan<<<1, 1024, 0, stream>>>(cursor, row_ptr);
    k_scatter<<<(EE + 255) / 256, 256, 0, stream>>>(dst, src, rel, norm, cursor, meta);

    // ---- weights ----
    k_wfull<<<NH / 4 / 256, 256, 0, stream>>>(V_in, comp_in, table);
    k_weights<<<(2 * 128 * 512) / 256, 256, 0, stream>>>(V_h, V_out, Bt_h, Bt_o);

    // ---- layer 1: table gather + relu -> h1 (bf16) ----
    k_agg1<<<NN / 4, 256, 0, stream>>>((const unsigned int*)table, row_ptr, meta, bias_in, h1u);

    // ---- layer 2: basis-agg -> g, GEMM -> h2 ----
    k_aggb<<<NN / 4, 256, 0, stream>>>(h1u, row_ptr, meta, comp_h, (unsigned int*)g);
    k_gemm2<<<469, 256, 0, stream>>>(g, Bt_h, bias_h, h2u, 1);

    // ---- layer 3: basis-agg -> g, GEMM -> h3 ----
    k_aggb<<<NN / 4, 256, 0, stream>>>(h2u, row_ptr, meta, comp_out, (unsigned int*)g);
    k_gemm2<<<469, 256, 0, stream>>>(g, Bt_o, bias_out, h3u, 0);

    // ---- attention pooling ----
    k_logits<<<NN / 4, 256, 0, stream>>>(h3u, gate_W, gate_b, logits);
    k_smax<<<1, 1024, 0, stream>>>(logits, scal);
    hipMemsetAsync(out, 0, 128 * sizeof(float), stream);
    k_out<<<(NN + 63) / 64, 64, 0, stream>>>(h3u, logits, scal, out);
}

// Round 3
// 413.703 us; speedup vs baseline: 1.4183x; 1.1278x over previous
//
#include <hip/hip_runtime.h>
#include <hip/hip_bf16.h>

// Problem constants (match reference setup_inputs()).
#define NN 30000
#define EE 480000
#define RR 8
#define BB 4
#define HH 128
#define NH (NN * HH)          // 3,840,000
#define SCAN_BLOCKS 118       // ceil(30000/256)

typedef __attribute__((ext_vector_type(8))) short short8;
typedef __attribute__((ext_vector_type(4))) float float4v;

__device__ __forceinline__ unsigned short f2bf(float f) {
    union { float f; unsigned int i; } c; c.f = f;
    unsigned int r = c.i + 0x7fffu + ((c.i >> 16) & 1u);
    return (unsigned short)(r >> 16);
}
__device__ __forceinline__ float bflo(unsigned int v) {
    union { unsigned int i; float f; } c; c.i = v << 16; return c.f;
}
__device__ __forceinline__ float bfhi(unsigned int v) {
    union { unsigned int i; float f; } c; c.i = v & 0xFFFF0000u; return c.f;
}
__device__ __forceinline__ unsigned int packbf(float a, float b) {
    return (unsigned int)f2bf(a) | ((unsigned int)f2bf(b) << 16);
}

// ---------------- CSR build ----------------
__global__ void k_hist(const int* __restrict__ dst, int* __restrict__ cnt) {
    int i = blockIdx.x * 256 + threadIdx.x;
    if (i < EE) atomicAdd(&cnt[dst[i]], 1);
}

// Parallel scan, stage A: per-block exclusive scan + block total.
__global__ __launch_bounds__(256)
void k_scan_a(const int* __restrict__ cc, int* __restrict__ rp, int* __restrict__ part) {
    __shared__ int wsum[4];
    int tid = threadIdx.x, lane = tid & 63, w = tid >> 6;
    int i = blockIdx.x * 256 + tid;
    int v = (i < NN) ? cc[i] : 0;
    int incl = v;
#pragma unroll
    for (int d = 1; d < 64; d <<= 1) {
        int t = __shfl_up(incl, d);
        if (lane >= d) incl += t;
    }
    if (lane == 63) wsum[w] = incl;
    __syncthreads();
    if (tid == 0) {
        int s = 0;
#pragma unroll
        for (int k = 0; k < 4; ++k) { int t = wsum[k]; wsum[k] = s; s += t; }
        part[blockIdx.x] = s;
    }
    __syncthreads();
    if (i < NN) rp[i] = wsum[w] + incl - v;
}

// Stage B: exclusive scan of the 118 block totals (1 block, 128 threads).
__global__ __launch_bounds__(128)
void k_scan_b(int* __restrict__ part) {
    __shared__ int wsum[2];
    int tid = threadIdx.x, lane = tid & 63, w = tid >> 6;
    int v = (tid < SCAN_BLOCKS) ? part[tid] : 0;
    int incl = v;
#pragma unroll
    for (int d = 1; d < 64; d <<= 1) {
        int t = __shfl_up(incl, d);
        if (lane >= d) incl += t;
    }
    if (lane == 63) wsum[w] = incl;
    __syncthreads();
    int off = (w == 1) ? wsum[0] : 0;
    if (tid < SCAN_BLOCKS) part[tid] = off + incl - v;
}

// Stage C: add block offsets; init cursor; set rp[NN]=EE.
__global__ __launch_bounds__(256)
void k_scan_c(int* __restrict__ rp, int* __restrict__ cur, const int* __restrict__ part) {
    int i = blockIdx.x * 256 + threadIdx.x;
    if (i < NN) {
        int v = rp[i] + part[blockIdx.x];
        rp[i] = v;
        cur[i] = v;
    }
    if (i == 0) rp[NN] = EE;
}

// Scatter packed edge meta into CSR order: x = src*64 | (rel<<24), y = bits(norm)
__global__ void k_scatter(const int* __restrict__ dst, const int* __restrict__ src,
                          const int* __restrict__ rel, const float* __restrict__ norm,
                          int* __restrict__ cursor, uint2* __restrict__ meta) {
    int i = blockIdx.x * 256 + threadIdx.x;
    if (i < EE) {
        int pos = atomicAdd(&cursor[dst[i]], 1);
        meta[pos] = make_uint2((unsigned int)(src[i] * 64) | ((unsigned int)rel[i] << 24),
                               __float_as_uint(norm[i]));
    }
}

// ---------------- Weight prep ----------------
// table[r][n][h] = sum_b comp_in[r][b] * V_in[b][n][h]   (bf16), 8 elems/lane, 16B stores
__global__ __launch_bounds__(256)
void k_wfull(const float* __restrict__ V_in, const float* __restrict__ comp_in,
             unsigned int* __restrict__ table_u) {
    int idx = (blockIdx.x * 256 + threadIdx.x) * 8;
    if (idx >= NH) return;
    float4v va[4], vb[4];
#pragma unroll
    for (int b = 0; b < 4; ++b) {
        va[b] = *(const float4v*)(V_in + b * NH + idx);
        vb[b] = *(const float4v*)(V_in + b * NH + idx + 4);
    }
#pragma unroll
    for (int r = 0; r < RR; ++r) {
        float c0 = comp_in[r * 4 + 0], c1 = comp_in[r * 4 + 1];
        float c2 = comp_in[r * 4 + 2], c3 = comp_in[r * 4 + 3];
        float4v oa = c0 * va[0] + c1 * va[1] + c2 * va[2] + c3 * va[3];
        float4v ob = c0 * vb[0] + c1 * vb[1] + c2 * vb[2] + c3 * vb[3];
        uint4 s;
        s.x = packbf(oa[0], oa[1]); s.y = packbf(oa[2], oa[3]);
        s.z = packbf(ob[0], ob[1]); s.w = packbf(ob[2], ob[3]);
        *(uint4*)(table_u + (r * NH + idx) / 2) = s;
    }
}

// Bt[j][kk] = Vflat[kk][j],  Vflat = V reshaped [512][128]  (B^T for MFMA B-frags)
__global__ void k_weights(const float* __restrict__ V_h, const float* __restrict__ V_o,
                          unsigned short* __restrict__ Bt_h, unsigned short* __restrict__ Bt_o) {
    int idx = blockIdx.x * 256 + threadIdx.x;   // 2 * 128 * 512 = 131072
    if (idx >= 2 * 128 * 512) return;
    int which = idx >> 16;
    int local = idx & 0xFFFF;
    int j = local >> 9;
    int kk = local & 511;
    const float* V = which ? V_o : V_h;
    unsigned short* W = which ? Bt_o : Bt_h;
    W[j * 512 + kk] = f2bf(V[kk * 128 + j]);
}

// ---------------- Layer-1 aggregation (unrolled x4 gathers in flight) ----------------
__global__ __launch_bounds__(256)
void k_agg1(const unsigned int* __restrict__ table_u, const int* __restrict__ row_ptr,
            const uint2* __restrict__ meta, const float* __restrict__ bias,
            unsigned int* __restrict__ h1u) {
    int lane = threadIdx.x & 63;
    int d = blockIdx.x * 4 + (threadIdx.x >> 6);
    int rs = row_ptr[d], re = row_ptr[d + 1];
    float a0 = 0.f, a1 = 0.f, b0 = 0.f, b1 = 0.f;
    for (int base = rs; base < re; base += 64) {
        int cnt = re - base; if (cnt > 64) cnt = 64;
        int rowm = 0; float wm = 0.f;
        if (lane < cnt) {
            uint2 m = meta[base + lane];
            rowm = (int)((m.x >> 24) * (unsigned int)(NN * 64) + (m.x & 0xFFFFFFu));
            wm = __uint_as_float(m.y);
        }
        int j = 0;
        for (; j + 4 <= cnt; j += 4) {
            int r0 = __shfl(rowm, j),     r1 = __shfl(rowm, j + 1);
            int r2 = __shfl(rowm, j + 2), r3 = __shfl(rowm, j + 3);
            float w0 = __shfl(wm, j),     w1 = __shfl(wm, j + 1);
            float w2 = __shfl(wm, j + 2), w3 = __shfl(wm, j + 3);
            unsigned int v0 = table_u[r0 + lane];
            unsigned int v1 = table_u[r1 + lane];
            unsigned int v2 = table_u[r2 + lane];
            unsigned int v3 = table_u[r3 + lane];
            a0 += w0 * bflo(v0); a1 += w0 * bfhi(v0);
            b0 += w1 * bflo(v1); b1 += w1 * bfhi(v1);
            a0 += w2 * bflo(v2); a1 += w2 * bfhi(v2);
            b0 += w3 * bflo(v3); b1 += w3 * bfhi(v3);
        }
        for (; j < cnt; ++j) {
            int r0 = __shfl(rowm, j);
            float w0 = __shfl(wm, j);
            unsigned int v0 = table_u[r0 + lane];
            a0 += w0 * bflo(v0); a1 += w0 * bfhi(v0);
        }
    }
    a0 += b0 + bias[2 * lane];
    a1 += b1 + bias[2 * lane + 1];
    a0 = fmaxf(a0, 0.f); a1 = fmaxf(a1, 0.f);
    h1u[d * 64 + lane] = packbf(a0, a1);
}

// ---------------- Basis-weighted aggregation (unrolled x4) ----------------
// g[d][b*128+h] = sum_e comp[rel_e][b] * norm_e * h[src_e][h]
__global__ __launch_bounds__(256)
void k_aggb(const unsigned int* __restrict__ hu, const int* __restrict__ row_ptr,
            const uint2* __restrict__ meta, const float* __restrict__ comp,
            unsigned int* __restrict__ gu) {
    int lane = threadIdx.x & 63;
    int d = blockIdx.x * 4 + (threadIdx.x >> 6);
    int rs = row_ptr[d], re = row_ptr[d + 1];
    float a00 = 0, a01 = 0, a10 = 0, a11 = 0, a20 = 0, a21 = 0, a30 = 0, a31 = 0;
    for (int base = rs; base < re; base += 64) {
        int cnt = re - base; if (cnt > 64) cnt = 64;
        int offm = 0; float w0m = 0, w1m = 0, w2m = 0, w3m = 0;
        if (lane < cnt) {
            uint2 m = meta[base + lane];
            offm = (int)(m.x & 0xFFFFFFu);
            int r4 = (int)(m.x >> 24) * 4;
            float nm = __uint_as_float(m.y);
            w0m = comp[r4 + 0] * nm; w1m = comp[r4 + 1] * nm;
            w2m = comp[r4 + 2] * nm; w3m = comp[r4 + 3] * nm;
        }
        int j = 0;
        for (; j + 4 <= cnt; j += 4) {
            int o0 = __shfl(offm, j),     o1 = __shfl(offm, j + 1);
            int o2 = __shfl(offm, j + 2), o3 = __shfl(offm, j + 3);
            unsigned int v0 = hu[o0 + lane];
            unsigned int v1 = hu[o1 + lane];
            unsigned int v2 = hu[o2 + lane];
            unsigned int v3 = hu[o3 + lane];
#pragma unroll
            for (int e = 0; e < 4; ++e) {
                unsigned int v = e == 0 ? v0 : (e == 1 ? v1 : (e == 2 ? v2 : v3));
                float w0 = __shfl(w0m, j + e), w1 = __shfl(w1m, j + e);
                float w2 = __shfl(w2m, j + e), w3 = __shfl(w3m, j + e);
                float f0 = bflo(v), f1 = bfhi(v);
                a00 += w0 * f0; a01 += w0 * f1;
                a10 += w1 * f0; a11 += w1 * f1;
                a20 += w2 * f0; a21 += w2 * f1;
                a30 += w3 * f0; a31 += w3 * f1;
            }
        }
        for (; j < cnt; ++j) {
            int off = __shfl(offm, j);
            float w0 = __shfl(w0m, j), w1 = __shfl(w1m, j);
            float w2 = __shfl(w2m, j), w3 = __shfl(w3m, j);
            unsigned int v = hu[off + lane];
            float f0 = bflo(v), f1 = bfhi(v);
            a00 += w0 * f0; a01 += w0 * f1;
            a10 += w1 * f0; a11 += w1 * f1;
            a20 += w2 * f0; a21 += w2 * f1;
            a30 += w3 * f0; a31 += w3 * f1;
        }
    }
    gu[d * 256 +       lane] = packbf(a00, a01);
    gu[d * 256 +  64 + lane] = packbf(a10, a11);
    gu[d * 256 + 128 + lane] = packbf(a20, a21);
    gu[d * 256 + 192 + lane] = packbf(a30, a31);
}

// ---------------- GEMM: out[n][j] = relu?(g[n] @ Bt^T + bias), M=30016 N=128 K=512 -----
__global__ __launch_bounds__(256)
void k_gemm2(const unsigned short* __restrict__ A, const unsigned short* __restrict__ Bt,
             const float* __restrict__ bias, unsigned int* __restrict__ outu, int relu) {
    __shared__ float lds[64 * 132];
    int tid = threadIdx.x;
    int w = tid >> 6, lane = tid & 63;
    int mr = lane & 15, kq = lane >> 4;
    int m0 = (blockIdx.x * 4 + w) * 16;
    float4v z = {0.f, 0.f, 0.f, 0.f};
    float4v acc[8];
#pragma unroll
    for (int c = 0; c < 8; ++c) acc[c] = z;
    const unsigned short* arow = A + (m0 + mr) * 512 + kq * 8;
    const unsigned short* brow = Bt + mr * 512 + kq * 8;
#pragma unroll
    for (int kk = 0; kk < 16; ++kk) {
        short8 a = *(const short8*)(arow + kk * 32);
#pragma unroll
        for (int c = 0; c < 8; ++c) {
            short8 b = *(const short8*)(brow + c * 16 * 512 + kk * 32);
            acc[c] = __builtin_amdgcn_mfma_f32_16x16x32_bf16(a, b, acc[c], 0, 0, 0);
        }
    }
    // C/D layout: col = lane&15, row = (lane>>4)*4 + i  -> stage to LDS, store coalesced
#pragma unroll
    for (int c = 0; c < 8; ++c)
#pragma unroll
        for (int i = 0; i < 4; ++i)
            lds[(w * 16 + kq * 4 + i) * 132 + c * 16 + mr] = acc[c][i];
    __syncthreads();
    float b0 = bias[2 * lane], b1 = bias[2 * lane + 1];
    for (int it = 0; it < 16; ++it) {
        int node = m0 + it;
        if (node < NN) {
            float f0 = lds[(w * 16 + it) * 132 + 2 * lane] + b0;
            float f1 = lds[(w * 16 + it) * 132 + 2 * lane + 1] + b1;
            if (relu) { f0 = fmaxf(f0, 0.f); f1 = fmaxf(f1, 0.f); }
            outu[node * 64 + lane] = packbf(f0, f1);
        }
    }
}

// ---------------- Pooling ----------------
__global__ __launch_bounds__(256)
void k_logits(const unsigned int* __restrict__ h3u, const float* __restrict__ gW,
              const float* __restrict__ gb, float* __restrict__ logits) {
    int lane = threadIdx.x & 63;
    int n = blockIdx.x * 4 + (threadIdx.x >> 6);
    unsigned int v = h3u[n * 64 + lane];
    float s = bflo(v) * gW[2 * lane] + bfhi(v) * gW[2 * lane + 1];
#pragma unroll
    for (int off = 32; off; off >>= 1) s += __shfl_down(s, off);
    if (lane == 0) logits[n] = s + gb[0];
}

__global__ void k_smax(const float* __restrict__ logits, float* __restrict__ scal) {
    __shared__ float buf[1024];
    int tid = threadIdx.x;
    float m = -1e30f;
    for (int i = tid; i < NN; i += 1024) m = fmaxf(m, logits[i]);
    buf[tid] = m;
    __syncthreads();
    for (int off = 512; off; off >>= 1) {
        if (tid < off) buf[tid] = fmaxf(buf[tid], buf[tid + off]);
        __syncthreads();
    }
    float mx = buf[0];
    __syncthreads();
    float s = 0.f;
    for (int i = tid; i < NN; i += 1024) s += expf(logits[i] - mx);
    buf[tid] = s;
    __syncthreads();
    for (int off = 512; off; off >>= 1) {
        if (tid < off) buf[tid] += buf[tid + off];
        __syncthreads();
    }
    if (tid == 0) { scal[0] = mx; scal[1] = buf[0]; }
}

__global__ void k_weightify(float* __restrict__ logits, const float* __restrict__ scal) {
    int i = blockIdx.x * 256 + threadIdx.x;
    if (i < NN) logits[i] = __expf(logits[i] - scal[0]) / scal[1];
}

// out[2h,2h+1] += sum_n w(n) * h3[n][2h,2h+1], 256 nodes per 64-thread block
__global__ __launch_bounds__(64)
void k_out(const unsigned int* __restrict__ h3u, const float* __restrict__ wgt,
           float* __restrict__ out) {
    int h = threadIdx.x;
    int n0 = blockIdx.x * 256;
    int n1 = n0 + 256; if (n1 > NN) n1 = NN;
    float a0 = 0.f, a1 = 0.f, b0 = 0.f, b1 = 0.f;
    int n = n0;
    for (; n + 2 <= n1; n += 2) {
        float wa = wgt[n], wb = wgt[n + 1];
        unsigned int va = h3u[n * 64 + h];
        unsigned int vb = h3u[(n + 1) * 64 + h];
        a0 += wa * bflo(va); a1 += wa * bfhi(va);
        b0 += wb * bflo(vb); b1 += wb * bfhi(vb);
    }
    for (; n < n1; ++n) {
        float wa = wgt[n];
        unsigned int va = h3u[n * 64 + h];
        a0 += wa * bflo(va); a1 += wa * bfhi(va);
    }
    atomicAdd(&out[2 * h], a0 + b0);
    atomicAdd(&out[2 * h + 1], a1 + b1);
}

extern "C" void kernel_launch(void* const* d_in, const int* in_sizes, int n_in,
                              void* d_out, int out_size, void* d_ws, size_t ws_size,
                              hipStream_t stream) {
    const int* src = (const int*)d_in[1];
    const int* dst = (const int*)d_in[2];
    const int* rel = (const int*)d_in[3];
    const float* norm = (const float*)d_in[4];
    const float* V_in = (const float*)d_in[5];
    const float* comp_in = (const float*)d_in[6];
    const float* bias_in = (const float*)d_in[7];
    const float* V_h = (const float*)d_in[8];
    const float* comp_h = (const float*)d_in[9];
    const float* bias_h = (const float*)d_in[10];
    const float* V_out = (const float*)d_in[11];
    const float* comp_out = (const float*)d_in[12];
    const float* bias_out = (const float*)d_in[13];
    const float* gate_W = (const float*)d_in[14];
    const float* gate_b = (const float*)d_in[15];
    float* out = (float*)d_out;

    // Workspace layout (~89 MB). g reuses the table region (table dead after agg1).
    char* ws = (char*)d_ws;
    unsigned short* table = (unsigned short*)ws;                 // 61,440,000 B (R*N*H bf16)
    unsigned short* g = (unsigned short*)ws;                     // 30,736,384 B (30016*512 bf16)
    unsigned int* h1u = (unsigned int*)(ws + 61440000);          //  7,680,000
    unsigned int* h2u = (unsigned int*)(ws + 69120000);          //  7,680,000
    unsigned int* h3u = (unsigned int*)(ws + 76800000);          //  7,680,000
    unsigned short* Bt_h = (unsigned short*)(ws + 84480000);     //    131,072
    unsigned short* Bt_o = (unsigned short*)(ws + 84611072);     //    131,072
    int* row_ptr = (int*)(ws + 84742144);                        //    120,064
    int* cursor = (int*)(ws + 84862208);                         //    120,064
    uint2* meta = (uint2*)(ws + 84982272);                       //  3,840,000
    float* logits = (float*)(ws + 88822272);                     //    120,000
    float* scal = (float*)(ws + 88942272);                       //          8
    int* part = (int*)(ws + 88942280);                           //        512

    // ---- CSR by dst (parallel scan) ----
    hipMemsetAsync(cursor, 0, NN * sizeof(int), stream);
    k_hist<<<(EE + 255) / 256, 256, 0, stream>>>(dst, cursor);
    k_scan_a<<<SCAN_BLOCKS, 256, 0, stream>>>(cursor, row_ptr, part);
    k_scan_b<<<1, 128, 0, stream>>>(part);
    k_scan_c<<<SCAN_BLOCKS, 256, 0, stream>>>(row_ptr, cursor, part);
    k_scatter<<<(EE + 255) / 256, 256, 0, stream>>>(dst, src, rel, norm, cursor, meta);

    // ---- weights ----
    k_wfull<<<NH / 8 / 256, 256, 0, stream>>>(V_in, comp_in, (unsigned int*)table);
    k_weights<<<(2 * 128 * 512) / 256, 256, 0, stream>>>(V_h, V_out, Bt_h, Bt_o);

    // ---- layer 1: table gather + relu -> h1 (bf16) ----
    k_agg1<<<NN / 4, 256, 0, stream>>>((const unsigned int*)table, row_ptr, meta, bias_in, h1u);

    // ---- layer 2: basis-agg -> g, GEMM -> h2 ----
    k_aggb<<<NN / 4, 256, 0, stream>>>(h1u, row_ptr, meta, comp_h, (unsigned int*)g);
    k_gemm2<<<469, 256, 0, stream>>>(g, Bt_h, bias_h, h2u, 1);

    // ---- layer 3: basis-agg -> g, GEMM -> h3 ----
    k_aggb<<<NN / 4, 256, 0, stream>>>(h2u, row_ptr, meta, comp_out, (unsigned int*)g);
    k_gemm2<<<469, 256, 0, stream>>>(g, Bt_o, bias_out, h3u, 0);

    // ---- attention pooling ----
    k_logits<<<NN / 4, 256, 0, stream>>>(h3u, gate_W, gate_b, logits);
    k_smax<<<1, 1024, 0, stream>>>(logits, scal);
    k_weightify<<<(NN + 255) / 256, 256, 0, stream>>>(logits, scal);
    hipMemsetAsync(out, 0, 128 * sizeof(float), stream);
    k_out<<<(NN + 255) / 256, 64, 0, stream>>>(h3u, logits, out);
}